// Round 7
// baseline (809.403 us; speedup 1.0000x reference)
//
#include <hip/hip_runtime.h>
#include <hip/hip_bf16.h>
#include <stdint.h>

#define QMAXF 127.0f

typedef __attribute__((ext_vector_type(4))) float f32x4;
typedef __attribute__((ext_vector_type(4))) int i32x4;

typedef __attribute__((address_space(1))) void gbl_void;
typedef __attribute__((address_space(3))) void lds_void;

__device__ __forceinline__ void gload_lds16(const void* g, void* l) {
    __builtin_amdgcn_global_load_lds((const gbl_void*)g, (lds_void*)l, 16, 0, 0);
}

// ---------------------------------------------------------------------------
// Kernel 1: per-token, per-128-col-group INT8 quant of activations.
// Outputs: q_x int8 [T,K]; scale transposed sxT[kb][T] (f32).
// ---------------------------------------------------------------------------
__global__ __launch_bounds__(256) void qd_x_kernel(const float* __restrict__ x,
                                                   char* __restrict__ qx,
                                                   float* __restrict__ sxT,
                                                   long ngroups, int nkb, int T) {
    long gw = ((long)blockIdx.x * blockDim.x + threadIdx.x) >> 6;
    int lane = threadIdx.x & 63;
    if (gw >= ngroups) return;

    float2 v = *(reinterpret_cast<const float2*>(x) + gw * 64 + lane);
    float a = fmaxf(fabsf(v.x), fabsf(v.y));
#pragma unroll
    for (int off = 32; off; off >>= 1) a = fmaxf(a, __shfl_xor(a, off));

    float scale = a > 0.f ? a / QMAXF : 1.f;
    int q0 = (int)fminf(fmaxf(rintf(v.x / scale), -QMAXF), QMAXF);
    int q1 = (int)fminf(fmaxf(rintf(v.y / scale), -QMAXF), QMAXF);
    unsigned short packed = (unsigned short)((q0 & 0xFF) | ((q1 & 0xFF) << 8));
    reinterpret_cast<unsigned short*>(qx)[gw * 64 + lane] = packed;

    if (lane == 0) {
        int t = (int)(gw / nkb), kb = (int)(gw - (long)t * nkb);
        sxT[(size_t)kb * T + t] = scale;
    }
}

// ---------------------------------------------------------------------------
// Kernel 2: 128x128 blockwise INT8 quant of weights.
// ---------------------------------------------------------------------------
__global__ __launch_bounds__(256) void qd_w_kernel(const float* __restrict__ w,
                                                   char* __restrict__ qw,
                                                   float* __restrict__ sw,
                                                   int K, int nkb) {
    int kb = blockIdx.x, ob = blockIdx.y;
    size_t base = (size_t)ob * 128 * K + (size_t)kb * 128;
    int t = threadIdx.x;

    float4 v[16];
    float a = 0.f;
#pragma unroll
    for (int i = 0; i < 16; i++) {
        int f = i * 256 + t;
        int row = f >> 5, c4 = f & 31;
        v[i] = *reinterpret_cast<const float4*>(w + base + (size_t)row * K + c4 * 4);
        a = fmaxf(a, fmaxf(fmaxf(fabsf(v[i].x), fabsf(v[i].y)),
                           fmaxf(fabsf(v[i].z), fabsf(v[i].w))));
    }
#pragma unroll
    for (int off = 32; off; off >>= 1) a = fmaxf(a, __shfl_xor(a, off));

    __shared__ float red[4];
    if ((t & 63) == 0) red[t >> 6] = a;
    __syncthreads();
    a = fmaxf(fmaxf(red[0], red[1]), fmaxf(red[2], red[3]));

    float scale = a > 0.f ? a / QMAXF : 1.f;
    if (t == 0) sw[(size_t)ob * nkb + kb] = scale;
#pragma unroll
    for (int i = 0; i < 16; i++) {
        int f = i * 256 + t;
        int row = f >> 5, c4 = f & 31;
        int q0 = (int)fminf(fmaxf(rintf(v[i].x / scale), -QMAXF), QMAXF);
        int q1 = (int)fminf(fmaxf(rintf(v[i].y / scale), -QMAXF), QMAXF);
        int q2 = (int)fminf(fmaxf(rintf(v[i].z / scale), -QMAXF), QMAXF);
        int q3 = (int)fminf(fmaxf(rintf(v[i].w / scale), -QMAXF), QMAXF);
        unsigned int p = (q0 & 0xFF) | ((q1 & 0xFF) << 8) | ((q2 & 0xFF) << 16) |
                         ((unsigned int)(q3 & 0xFF) << 24);
        *reinterpret_cast<unsigned int*>(qw + base + (size_t)row * K + c4 * 4) = p;
    }
}

// ---------------------------------------------------------------------------
// Kernel 3: exact INT8 GEMM, 256x256 tile, BK=64 substeps, ring-3 LDS
// (A 16K + B 16K + sx 1K per slot = 99 KB), ONE barrier per substep:
//   { WAITV(5) -> BAR -> stage substep j+2 (5 gloads) -> compute j }.
// Loads fly ~2 substeps; vmcnt never drains in-loop. BK64 swizzle:
// phys_chunk = c ^ ((row>>1)&3) (verified 8 beats/bank, conflict-free).
// FIX per substep (exact: |iacc| < 2^20). sw via lane-indexed VGPR + shfl.
// ---------------------------------------------------------------------------
#define GBM 256
#define GBN 256
#define SUBK 64
#define A_BY 16384
#define B_BY 16384
#define SX_BY 1024
#define SLOT_BY (A_BY + B_BY + SX_BY)   // 33792
#define RING 3

#define BAR()                              \
    do {                                   \
        asm volatile("" ::: "memory");     \
        __builtin_amdgcn_s_barrier();      \
        asm volatile("" ::: "memory");     \
    } while (0)
#define WAITL0()                                          \
    do {                                                  \
        asm volatile("s_waitcnt lgkmcnt(0)" ::: "memory");\
        __builtin_amdgcn_sched_barrier(0);                \
    } while (0)
#define WAITV(n) asm volatile("s_waitcnt vmcnt(" #n ")" ::: "memory")

__global__ __launch_bounds__(512, 1) void gemm_i8_kernel(
    const char* __restrict__ Aq,    // [M,K] int8
    const char* __restrict__ Bq,    // [N,K] int8
    const float* __restrict__ sxT,  // [K/128][M]
    const float* __restrict__ swp,  // [N/128][K/128]
    const float* __restrict__ bias,
    float* __restrict__ C,          // [M,N] f32
    int M, int N, int K) {
    __shared__ alignas(16) unsigned char lds8[RING * SLOT_BY];  // 99 KiB

    int nTm = M / GBM, nTn = N / GBN;
    int nwg = gridDim.x, wg = blockIdx.x;
    int mt, nt;
    if ((nTm & 7) == 0 && (32 % (nTm >> 3)) == 0) {
        // XCD-aware 2D window (R5): each XCD owns nTm/8 mt-rows; its 32
        // co-resident blocks form a (nTm/8) x G window sharing L2 panels.
        int x = wg & 7, j = wg >> 3;
        int mper = nTm >> 3;
        int G = 32 / mper;
        int wsz = mper * G;
        int fullw = nTn / G;
        int jfull = fullw * wsz;
        int g, r, width;
        if (j < jfull) { g = j / wsz; r = j - g * wsz; width = G; }
        else { g = fullw; r = j - jfull; width = nTn - fullw * G; }
        mt = x * mper + r / width;
        nt = g * G + r % width;
    } else {
        int swz = (nwg & 7) ? wg : ((wg & 7) * (nwg >> 3) + (wg >> 3));
        mt = swz / nTn; nt = swz - mt * nTn;
    }

    int t = threadIdx.x, wid = t >> 6, lane = t & 63;
    int wm = wid >> 2, wn = wid & 3;   // 2 x 4 wave grid; wave tile 128x64
    int lr = lane & 15, lq = lane >> 4;
    int nkb = K >> 7;
    int NSUB = K / SUBK;               // 64

    const char* Abase = Aq + (size_t)mt * GBM * K;
    const char* Bbase = Bq + (size_t)nt * GBN * K;

    // Staging geometry: tile 256 rows x 64 B = 1024 chunks of 16 B; thread t
    // covers phys chunks t (rows 0-127) and 512+t (rows 128-255; same column
    // swizzle since row+128 preserves (row>>1)&3... (row>>1)&3 of row+128 ==
    // (row>>1 + 64)&3 == same). Source pre-swizzled: logical chunk =
    // phys ^ ((row>>1)&3).
    {
    }
    int rA0 = t >> 2;
    int pcc = t & 3;
    int cA0 = (pcc ^ ((rA0 >> 1) & 3)) << 4;   // byte col offset within 64B row
    const char* gA = Abase + (size_t)rA0 * K + cA0;
    const char* gB = Bbase + (size_t)rA0 * K + cA0;
    const char* gSX = (const char*)sxT + ((size_t)mt * GBM + (t & 63) * 4) * 4;
    size_t rowStep = (size_t)128 * K;

    auto STAGE = [&](int slot, int j) {
        size_t kb = (size_t)j * SUBK;
        unsigned char* sb = lds8 + slot * SLOT_BY;
        gload_lds16(gA + kb, sb + t * 16);
        gload_lds16(gA + rowStep + kb, sb + (512 + t) * 16);
        gload_lds16(gB + kb, sb + A_BY + t * 16);
        gload_lds16(gB + rowStep + kb, sb + A_BY + (512 + t) * 16);
        gload_lds16(gSX + (size_t)(j >> 1) * M * 4, sb + A_BY + B_BY + (t & 63) * 16);
    };

    // Fragment read offsets (bytes within slot). phys = lq ^ ((lr>>1)&3)
    // (frag row = 16*q + lr, so (row>>1)&3 == (lr>>1)&3).
    int physXor = (lq ^ ((lr >> 1) & 3)) << 4;
    int offA[2][4], offB[4], offSX[2][4];
#pragma unroll
    for (int mq = 0; mq < 2; mq++)
#pragma unroll
        for (int m = 0; m < 4; m++) {
            int row = wm * 128 + mq * 64 + m * 16;
            offA[mq][m] = (row + lr) * 64 + physXor;
            offSX[mq][m] = A_BY + B_BY + (row + lq * 4) * 4;
        }
#pragma unroll
    for (int n = 0; n < 4; n++)
        offB[n] = A_BY + (wn * 64 + n * 16 + lr) * 64 + physXor;

    f32x4 facc[8][4];
#pragma unroll
    for (int m = 0; m < 8; m++)
#pragma unroll
        for (int n = 0; n < 4; n++) facc[m][n] = (f32x4){0.f, 0.f, 0.f, 0.f};

    // Per-wave weight scales for this block's two o-128-blocks: lane kb holds
    // swp[obk][kb]; broadcast per substep via shfl.
    float swv = (lane < nkb) ? swp[(size_t)(nt * 2 + (wn >> 1)) * nkb + lane] : 0.f;

    auto COMPUTE = [&](int slot, float swq) {
        const unsigned char* sb = lds8 + slot * SLOT_BY;
        i32x4 b[4];
#pragma unroll
        for (int n = 0; n < 4; n++)
            b[n] = *reinterpret_cast<const i32x4*>(sb + offB[n]);
#pragma unroll
        for (int mq = 0; mq < 2; mq++) {
            i32x4 a[4];
            f32x4 sx4[4];
#pragma unroll
            for (int m = 0; m < 4; m++)
                a[m] = *reinterpret_cast<const i32x4*>(sb + offA[mq][m]);
#pragma unroll
            for (int m = 0; m < 4; m++)
                sx4[m] = *reinterpret_cast<const f32x4*>(sb + offSX[mq][m]);
            WAITL0();
            __builtin_amdgcn_s_setprio(1);
#pragma unroll
            for (int nq = 0; nq < 2; nq++) {
                i32x4 ia[4][2];
#pragma unroll
                for (int m = 0; m < 4; m++)
#pragma unroll
                    for (int n2 = 0; n2 < 2; n2++)
                        ia[m][n2] = __builtin_amdgcn_mfma_i32_16x16x64_i8(
                            a[m], b[nq * 2 + n2], (i32x4){0, 0, 0, 0}, 0, 0, 0);
#pragma unroll
                for (int m = 0; m < 4; m++) {
                    f32x4 s = sx4[m] * swq;
#pragma unroll
                    for (int n2 = 0; n2 < 2; n2++) {
                        f32x4 cv;
#pragma unroll
                        for (int r = 0; r < 4; r++) cv[r] = (float)ia[m][n2][r];
                        facc[mq * 4 + m][nq * 2 + n2] += cv * s;
                    }
                }
            }
            __builtin_amdgcn_s_setprio(0);
        }
    };

    // Prologue: sw scales (1 vmem) + stage substeps 0,1 (5 each).
    STAGE(0, 0);
    STAGE(1, 1);

    for (int j = 0; j < NSUB; ++j) {
        WAITV(5);                 // substep j resident (leaves j+1's 5 in flight)
        BAR();                    // publish j; all waves past reads of slot (j+2)%3
        int jn = j + 2 > NSUB - 1 ? NSUB - 1 : j + 2;
        STAGE((j + 2) % RING, jn);
        float swq = __shfl(swv, j >> 1);
        COMPUTE(j % RING, swq);
    }
    asm volatile("s_waitcnt vmcnt(0)" ::: "memory");  // drain dup tail stages

    // Epilogue: bias + store. C/D layout: col = lane&15, row = (lane>>4)*4 + reg.
    float bvv[4];
#pragma unroll
    for (int n = 0; n < 4; n++) bvv[n] = bias[nt * GBN + wn * 64 + n * 16 + lr];

#pragma unroll
    for (int m = 0; m < 8; m++) {
#pragma unroll
        for (int r = 0; r < 4; r++) {
            size_t row = (size_t)(mt * GBM + wm * 128 + m * 16 + lq * 4 + r);
            float* Crow = C + row * N + nt * GBN + wn * 64 + lr;
#pragma unroll
            for (int n = 0; n < 4; n++) Crow[n * 16] = facc[m][n][r] + bvv[n];
        }
    }
}

extern "C" void kernel_launch(void* const* d_in, const int* in_sizes, int n_in,
                              void* d_out, int out_size, void* d_ws, size_t ws_size,
                              hipStream_t stream) {
    const float* x = (const float*)d_in[0];
    const float* w = (const float*)d_in[1];
    const float* bias = (const float*)d_in[2];
    float* y = (float*)d_out;

    int O = in_sizes[2];          // 11008
    int K = in_sizes[1] / O;      // 4096
    int T = in_sizes[0] / K;      // 8192 tokens
    int nkb = K / 128;            // 32

    char* qx = (char*)d_ws;
    size_t off = ((size_t)T * K + 255) & ~(size_t)255;
    char* qw = (char*)d_ws + off;
    off += ((size_t)O * K + 255) & ~(size_t)255;
    float* sxT = (float*)((char*)d_ws + off);
    off += ((size_t)nkb * T * 4 + 255) & ~(size_t)255;
    float* sw = (float*)((char*)d_ws + off);

    long ngroups = (long)T * nkb;
    qd_x_kernel<<<dim3((unsigned)((ngroups + 3) / 4)), dim3(256), 0, stream>>>(
        x, qx, sxT, ngroups, nkb, T);
    qd_w_kernel<<<dim3(nkb, O / 128), dim3(256), 0, stream>>>(w, qw, sw, K, nkb);

    int grid = (T / GBM) * (O / GBN);
    gemm_i8_kernel<<<dim3(grid), dim3(512), 0, stream>>>(qx, qw, sxT, sw, bias, y,
                                                         T, O, K);
}